// Round 8
// baseline (1596.873 us; speedup 1.0000x reference)
//
#include <hip/hip_runtime.h>

#define N_NODES 50000
#define N_EDGES 800000
#define D_IN    512
#define D_OUT   128
#define N_SUP   2
#define N_COLS  (N_SUP * D_OUT)            // 256 combined output cols
#define NB_S    391                        // 128-row buckets per support
#define NB      (N_SUP * NB_S)             // 782 buckets
#define CAP     2304                       // bucket capacity (mean 2048 + 5.7 sigma)
#define CHUNK   3125                       // 800000 = 256 * 3125 exactly
#define NROWT   391                        // ceil(50000/128) gemm row-tiles
#define GC_GRID 512                        // 4 col-groups x 128 row-slots
#define ACC_LD  129                        // LDS accumulator row stride (bank spread)

typedef __attribute__((ext_vector_type(8))) __bf16 bf16x8;
typedef __attribute__((ext_vector_type(4))) float  f32x4;

// ---------------------------------------------------------------------------
// K1: W fp32 -> bf16 in staging order (chunk g = (k>>3)*256 + col) + zero
// gcursor.
// ---------------------------------------------------------------------------
__global__ __launch_bounds__(256) void convert_w(const float* __restrict__ w,
                                                 __bf16* __restrict__ wt2,
                                                 int* __restrict__ gcursor) {
    const int g = blockIdx.x * 256 + threadIdx.x;     // 16384 chunks
    if (g < NB) gcursor[g] = 0;
    if (g >= (D_IN / 8) * N_COLS) return;
    const int kq = g >> 8;
    const int n  = g & 255;
    const int s  = n >> 7;
    const int np = n & 127;
    bf16x8 v;
#pragma unroll
    for (int j = 0; j < 8; ++j)
        v[j] = (__bf16)w[((size_t)s * D_IN + kq * 8 + j) * D_OUT + np];
    *(bf16x8*)(wt2 + (size_t)g * 8) = v;
}

// ---------------------------------------------------------------------------
// K2: fused GEMM + coarse scatter. 512 blocks x 512 threads.
// Phase 1: B 64-col slice in 64 KB LDS (loaded once via global_load_lds),
// barrier-free main loop with an explicit 4-deep A software pipeline
// (8 float4 in flight per lane — round-7 lesson: VGPR=52 meant ZERO overlap,
// each K-step serially exposed ~200-900 cyc of load latency).
// Phase 2: counting sort of one 3125-edge chunk into 128-row buckets.
// ---------------------------------------------------------------------------
__global__ __launch_bounds__(512) void gemm_coarse(const float* __restrict__ x,
                                                   const __bf16* __restrict__ wt2,
                                                   __bf16* __restrict__ pre,
                                                   const float* __restrict__ adj_vals,
                                                   const int* __restrict__ adj_rows,
                                                   const int* __restrict__ adj_cols,
                                                   int* __restrict__ gcursor,
                                                   uint2* __restrict__ coarse) {
    __shared__ __align__(16) char smem[65536];   // gemm: 64 KB B; coarse: 33.3 KB
    const int t   = threadIdx.x;
    const int bid = blockIdx.x;

    // ================= Phase 1: GEMM pre[s] = bf16(x) @ bf16(W[s]) ========
    {
        __bf16* Bs = (__bf16*)smem;            // 64 kq x 64 cols x bf16x8 = 64 KB
        const int g       = bid >> 7;          // col-group 0..3 (64 cols each)
        const int rowslot = bid & 127;
        const int wv      = t >> 6;            // wave 0..7 -> rows wv*16..+16
        const int lane    = t & 63;
        const int l15     = lane & 15;
        const int quad    = lane >> 4;
        const int s_out   = g >> 1;            // support
        const int cbase   = (g & 1) * 64;      // col base within support

        // ---- stage B slice into LDS (once) ----
#pragma unroll
        for (int it = 0; it < 8; ++it) {
            const int i    = it * 512 + t;     // 0..4095
            const int kq   = i >> 6;
            const int cloc = i & 63;
            const __bf16* gsrc = wt2 + ((size_t)(kq * 256 + g * 64 + cloc)) * 8;
            __builtin_amdgcn_global_load_lds(
                (const __attribute__((address_space(1))) unsigned int*)gsrc,
                (__attribute__((address_space(3))) unsigned int*)(Bs + (size_t)i * 8),
                16, 0, 0);
        }
        __syncthreads();                       // B resident; no barriers after

        for (int tile = rowslot; tile < NROWT; tile += 128) {
            const int rbase = tile * 128 + wv * 16;
            if (rbase + 16 > N_NODES) continue;
            const float* arow = x + (size_t)(rbase + l15) * D_IN + quad * 8;

            f32x4 acc0 = (f32x4)0.f, acc1 = (f32x4)0.f;
            f32x4 acc2 = (f32x4)0.f, acc3 = (f32x4)0.f;

            auto kstep = [&](int kb, float4 u, float4 v) {
                bf16x8 a;
                a[0] = (__bf16)u.x; a[1] = (__bf16)u.y;
                a[2] = (__bf16)u.z; a[3] = (__bf16)u.w;
                a[4] = (__bf16)v.x; a[5] = (__bf16)v.y;
                a[6] = (__bf16)v.z; a[7] = (__bf16)v.w;
                const __bf16* bb = Bs + ((size_t)(kb * 4 + quad) * 64 + l15) * 8;
                const bf16x8 b0 = *(const bf16x8*)(bb);
                const bf16x8 b1 = *(const bf16x8*)(bb + 128);
                const bf16x8 b2 = *(const bf16x8*)(bb + 256);
                const bf16x8 b3 = *(const bf16x8*)(bb + 384);
                acc0 = __builtin_amdgcn_mfma_f32_16x16x32_bf16(a, b0, acc0, 0, 0, 0);
                acc1 = __builtin_amdgcn_mfma_f32_16x16x32_bf16(a, b1, acc1, 0, 0, 0);
                acc2 = __builtin_amdgcn_mfma_f32_16x16x32_bf16(a, b2, acc2, 0, 0, 0);
                acc3 = __builtin_amdgcn_mfma_f32_16x16x32_bf16(a, b3, acc3, 0, 0, 0);
            };
#define LDA(Pa, Pb, KB) { const float4* _ap = (const float4*)(arow + (KB) * 32); \
                          Pa = _ap[0]; Pb = _ap[1]; }
            float4 u0, u1, v0, v1, w0, w1, z0, z1;
            LDA(u0, u1, 0) LDA(v0, v1, 1) LDA(w0, w1, 2) LDA(z0, z1, 3)
#pragma unroll
            for (int k4 = 0; k4 < 4; ++k4) {
                kstep(k4 * 4 + 0, u0, u1); if (k4 < 3) LDA(u0, u1, k4 * 4 + 4)
                kstep(k4 * 4 + 1, v0, v1); if (k4 < 3) LDA(v0, v1, k4 * 4 + 5)
                kstep(k4 * 4 + 2, w0, w1); if (k4 < 3) LDA(w0, w1, k4 * 4 + 6)
                kstep(k4 * 4 + 3, z0, z1); if (k4 < 3) LDA(z0, z1, k4 * 4 + 7)
            }
#undef LDA

            // C layout: col = lane&15, row = quad*4 + r  [m89-verified]
            __bf16* dst = pre + ((size_t)s_out * N_NODES + rbase + quad * 4) * D_OUT
                              + cbase + l15;
#pragma unroll
            for (int r = 0; r < 4; ++r) {
                dst[(size_t)r * D_OUT]      = (__bf16)acc0[r];
                dst[(size_t)r * D_OUT + 16] = (__bf16)acc1[r];
                dst[(size_t)r * D_OUT + 32] = (__bf16)acc2[r];
                dst[(size_t)r * D_OUT + 48] = (__bf16)acc3[r];
            }
        }
    }
    __syncthreads();   // LDS handoff P1 -> P2 (block-local dependency only)

    // ================= Phase 2: coarse scatter (one 3125-edge chunk) ======
    {
        int*   hist  = (int*)smem;                  // 391
        int*   excl  = hist + NB_S;                 // 391
        int*   lbase = excl + NB_S;                 // 391
        int*   rankc = lbase + NB_S;                // 391  (ends 6256 B)
        int*   sc    = rankc + NB_S;                // 512  (ends 8304 B)
        uint2* buf   = (uint2*)(smem + 8320);       // 3125 * 8 = 25000 B

        const int s  = bid >> 8;                    // support
        const int ch = bid & 255;                   // chunk 0..255
        if (t < NB_S) { hist[t] = 0; rankc[t] = 0; }
        __syncthreads();

        const int e0 = ch * CHUNK;
        int   rr[7]; int cc[7]; float vv[7];
#pragma unroll
        for (int i = 0; i < 7; ++i) {
            const int idx = i * 512 + t;
            if (idx < CHUNK) {
                const size_t src = (size_t)s * N_EDGES + e0 + idx;
                rr[i] = adj_rows[src];
                cc[i] = adj_cols[src];
                vv[i] = adj_vals[src];
                atomicAdd(&hist[rr[i] >> 7], 1);
            } else {
                rr[i] = -1; cc[i] = 0; vv[i] = 0.f;
            }
        }
        __syncthreads();

        sc[t] = (t < NB_S) ? hist[t] : 0;
        __syncthreads();
        for (int off = 1; off < 512; off <<= 1) {
            const int a = (t >= off) ? sc[t - off] : 0;
            __syncthreads();
            sc[t] += a;
            __syncthreads();
        }
        if (t < NB_S) {
            excl[t]  = sc[t] - hist[t];
            lbase[t] = hist[t] ? atomicAdd(&gcursor[s * NB_S + t], hist[t]) : 0;
        }
        __syncthreads();

#pragma unroll
        for (int i = 0; i < 7; ++i) {
            if (rr[i] >= 0) {
                const int b   = rr[i] >> 7;
                const int pos = excl[b] + atomicAdd(&rankc[b], 1);
                buf[pos] = make_uint2(__float_as_uint(vv[i]),
                                      ((unsigned)rr[i] << 16) | (unsigned)cc[i]);
            }
        }
        __syncthreads();

        for (int i = t; i < CHUNK; i += 512) {
            const uint2 ed = buf[i];
            const int b   = (int)(ed.y >> 23);      // r>>7 (r is 16 bits)
            const int dst = lbase[b] + (i - excl[b]);
            if (dst < CAP)                          // statistically impossible overflow guard
                coarse[(size_t)(s * NB_S + b) * CAP + dst] = ed;
        }
    }
}

// ---------------------------------------------------------------------------
// K3: bucket gather — one block per 128-row bucket, BOTH supports.
// f32 accumulator [128][129] in LDS (66 KB; stride 129 spreads banks).
// Quarter-wave per edge: 16 lanes x uint4 = full 256 B pre row; products
// atomicAdd'ed into LDS; bias+ReLU+coalesced writeout. Replaces scatter_fine
// + gather_spmm (no row sort, no `sorted` buffer).
// ---------------------------------------------------------------------------
__global__ __launch_bounds__(512) void bucket_gather(const uint2* __restrict__ coarse,
                                                     const int* __restrict__ gcursor,
                                                     const uint4* __restrict__ pre_q,
                                                     const float* __restrict__ bias,
                                                     float* __restrict__ out) {
    __shared__ float acc[128 * ACC_LD];             // 66048 B
    const int bk   = blockIdx.x;                    // 0..390
    const int t    = threadIdx.x;
    const int lane = t & 63;
    const int q    = lane >> 4;                     // quarter -> edge j*4+q
    const int fl   = lane & 15;                     // features fl*8 .. fl*8+7
    const int wv   = t >> 6;                        // 8 waves

    for (int i = t; i < 128 * ACC_LD; i += 512) acc[i] = 0.f;
    __syncthreads();

#pragma unroll
    for (int s = 0; s < N_SUP; ++s) {
        const int bkt  = s * NB_S + bk;
        const size_t b0 = (size_t)bkt * CAP;
        const int cnt  = min(gcursor[bkt], CAP);
        const uint4* psup = pre_q + (size_t)s * N_NODES * 16 + fl;

        for (int e0 = wv * 64; e0 < cnt; e0 += 512) {
            const int m = min(64, cnt - e0);
            float v = 0.f; int c = 0, r = 0;
            if (lane < m) {
                const uint2 ed = coarse[b0 + e0 + lane];
                v = __uint_as_float(ed.x);
                c = (int)(ed.y & 0xFFFFu);
                r = (int)((ed.y >> 16) & 127u);
            }
#pragma unroll 4
            for (int j = 0; j < 16; ++j) {
                const int jj = j * 4 + q;
                const float vj = __shfl(v, jj);
                const int   cj = __shfl(c, jj);
                const int   rj = __shfl(r, jj);
                if (jj < m) {
                    const uint4 p = psup[(size_t)cj * 16];
                    float* ar = &acc[rj * ACC_LD + fl * 8];
                    atomicAdd(ar + 0, vj * __uint_as_float(p.x << 16));
                    atomicAdd(ar + 1, vj * __uint_as_float(p.x & 0xffff0000u));
                    atomicAdd(ar + 2, vj * __uint_as_float(p.y << 16));
                    atomicAdd(ar + 3, vj * __uint_as_float(p.y & 0xffff0000u));
                    atomicAdd(ar + 4, vj * __uint_as_float(p.z << 16));
                    atomicAdd(ar + 5, vj * __uint_as_float(p.z & 0xffff0000u));
                    atomicAdd(ar + 6, vj * __uint_as_float(p.w << 16));
                    atomicAdd(ar + 7, vj * __uint_as_float(p.w & 0xffff0000u));
                }
            }
        }
    }
    __syncthreads();

    // writeout: thread -> (row t>>2, col-quarter t&3), 8 float4 each
    const int rloc = t >> 2;
    const int qt   = t & 3;
    const int row  = bk * 128 + rloc;
    if (row < N_NODES) {
        const float* ar = &acc[rloc * ACC_LD + qt * 32];
        const float* bs = bias + qt * 32;
        float* dst = out + (size_t)row * D_OUT + qt * 32;
#pragma unroll
        for (int i = 0; i < 8; ++i) {
            float4 a4 = { ar[i * 4], ar[i * 4 + 1], ar[i * 4 + 2], ar[i * 4 + 3] };
            const float4 b4 = *(const float4*)(bs + i * 4);
            float4 o;
            o.x = fmaxf(a4.x + b4.x, 0.f);
            o.y = fmaxf(a4.y + b4.y, 0.f);
            o.z = fmaxf(a4.z + b4.z, 0.f);
            o.w = fmaxf(a4.w + b4.w, 0.f);
            *(float4*)(dst + i * 4) = o;
        }
    }
}

extern "C" void kernel_launch(void* const* d_in, const int* in_sizes, int n_in,
                              void* d_out, int out_size, void* d_ws, size_t ws_size,
                              hipStream_t stream) {
    const float* x        = (const float*)d_in[0];
    const float* kernels  = (const float*)d_in[1];
    const float* bias     = (const float*)d_in[2];
    const float* adj_vals = (const float*)d_in[3];
    const int*   adj_rows = (const int*)d_in[4];
    const int*   adj_cols = (const int*)d_in[5];
    float* out = (float*)d_out;

    // ---- workspace layout ----
    char* ws = (char*)d_ws;
    size_t off = 0;
    auto alloc = [&](size_t bytes) {
        char* p = ws + off;
        off += (bytes + 255) & ~(size_t)255;
        return p;
    };
    __bf16* pre    = (__bf16*)alloc(sizeof(__bf16) * N_SUP * N_NODES * D_OUT); // 25.6 MB
    __bf16* wt2    = (__bf16*)alloc(sizeof(__bf16) * D_IN * N_COLS);           // 256 KB
    uint2*  coarse = (uint2*) alloc(sizeof(uint2)  * NB * CAP);                // 14.4 MB
    int*    gcursor = (int*)alloc(sizeof(int) * NB);                           // 3.1 KB

    // K1: W convert + gcursor zero
    convert_w<<<(D_IN / 8) * N_COLS / 256, 256, 0, stream>>>(kernels, wt2, gcursor);

    // K2: fused GEMM (B-in-LDS, pipelined A) + coarse scatter (128-row buckets)
    gemm_coarse<<<GC_GRID, 512, 0, stream>>>(x, wt2, pre,
                                             adj_vals, adj_rows, adj_cols,
                                             gcursor, coarse);

    // K3: bucket gather (LDS f32 accumulate + bias + ReLU)
    bucket_gather<<<NB_S, 512, 0, stream>>>(coarse, gcursor, (const uint4*)pre,
                                            bias, out);
}

// Round 9
// 261.274 us; speedup vs baseline: 6.1119x; 6.1119x over previous
//
#include <hip/hip_runtime.h>

#define N_NODES 50000
#define N_EDGES 800000
#define D_IN    512
#define D_OUT   128
#define N_SUP   2
#define N_COLS  (N_SUP * D_OUT)            // 256 combined output cols
#define NB_S    782                        // 64-row buckets per support
#define NB      (N_SUP * NB_S)             // 1564 buckets
#define CAPF    1280                       // bucket capacity (mean 1023 + 8 sigma)
#define CHUNK   3125                       // 800000 = 256 * 3125 exactly
#define TILE_R  16
#define NTILES  (N_NODES / TILE_R)         // 3125 exactly
#define GGRID   256                        // persistent gemm blocks

typedef __attribute__((ext_vector_type(8))) __bf16 bf16x8;
typedef __attribute__((ext_vector_type(4))) float  f32x4;

// ---------------------------------------------------------------------------
// K1: W fp32 -> bf16 in staging order (chunk g = (k>>3)*256 + col) + zero
// gcursor.
// ---------------------------------------------------------------------------
__global__ __launch_bounds__(256) void convert_w(const float* __restrict__ w,
                                                 __bf16* __restrict__ wt2,
                                                 int* __restrict__ gcursor) {
    const int g = blockIdx.x * 256 + threadIdx.x;     // 16384 chunks
    if (g < NB) gcursor[g] = 0;
    if (g >= (D_IN / 8) * N_COLS) return;
    const int kq = g >> 8;
    const int n  = g & 255;
    const int s  = n >> 7;
    const int np = n & 127;
    bf16x8 v;
#pragma unroll
    for (int j = 0; j < 8; ++j)
        v[j] = (__bf16)w[((size_t)s * D_IN + kq * 8 + j) * D_OUT + np];
    *(bf16x8*)(wt2 + (size_t)g * 8) = v;
}

// ---------------------------------------------------------------------------
// K2: GEMM (round-3 gemm_v2 verbatim — best measured ~45 us).
// B in registers (128 VGPR/wave = 32 cols x K=512), 8 waves cover 256 cols.
// A streamed through a 16 KB swizzled LDS tile, 2 barriers per tile.
// 256 persistent blocks grid-stride over 3125 tiles.
// ---------------------------------------------------------------------------
__global__ __launch_bounds__(512, 2) void gemm_bf16_v2(const float* __restrict__ x,
                                                       const __bf16* __restrict__ wt2,
                                                       __bf16* __restrict__ pre) {
    __shared__ __align__(16) __bf16 As[TILE_R * 64 * 8];   // 16 KB

    const int t    = threadIdx.x;
    const int lane = t & 63;
    const int w    = t >> 6;            // wave 0..7 -> cols [w*32, w*32+32)
    const int l15  = lane & 15;
    const int quad = lane >> 4;

    bf16x8 B0[16], B1[16];
#pragma unroll
    for (int kb = 0; kb < 16; ++kb) {
        const size_t g0 = (size_t)(kb * 4 + quad) * 256 + w * 32 + l15;
        B0[kb] = *(const bf16x8*)(wt2 + g0 * 8);
        B1[kb] = *(const bf16x8*)(wt2 + (g0 + 16) * 8);
    }

    const int s_out = w >> 2;
    const int cp0   = (w & 3) * 32 + l15;

    const int srow = t >> 5;            // 0..15
    const int sc0  = (t & 31) * 2;      // chunk pair
    const int swz  = srow & 7;

    int tile = blockIdx.x;
    float4 f0, f1, f2, f3;
    {
        const float* src = x + ((size_t)tile * TILE_R + srow) * D_IN + sc0 * 8;
        f0 = ((const float4*)src)[0];
        f1 = ((const float4*)src)[1];
        f2 = ((const float4*)src)[2];
        f3 = ((const float4*)src)[3];
    }

    while (tile < NTILES) {
        bf16x8 lo, hi;
        lo[0] = (__bf16)f0.x; lo[1] = (__bf16)f0.y; lo[2] = (__bf16)f0.z; lo[3] = (__bf16)f0.w;
        lo[4] = (__bf16)f1.x; lo[5] = (__bf16)f1.y; lo[6] = (__bf16)f1.z; lo[7] = (__bf16)f1.w;
        hi[0] = (__bf16)f2.x; hi[1] = (__bf16)f2.y; hi[2] = (__bf16)f2.z; hi[3] = (__bf16)f2.w;
        hi[4] = (__bf16)f3.x; hi[5] = (__bf16)f3.y; hi[6] = (__bf16)f3.z; hi[7] = (__bf16)f3.w;

        __syncthreads();
        *(bf16x8*)&As[((size_t)srow * 64 + (sc0       ^ swz)) * 8] = lo;
        *(bf16x8*)&As[((size_t)srow * 64 + ((sc0 + 1) ^ swz)) * 8] = hi;
        __syncthreads();

        const int next = tile + GGRID;
        if (next < NTILES) {
            const float* src = x + ((size_t)next * TILE_R + srow) * D_IN + sc0 * 8;
            f0 = ((const float4*)src)[0];
            f1 = ((const float4*)src)[1];
            f2 = ((const float4*)src)[2];
            f3 = ((const float4*)src)[3];
        }

        f32x4 acc0 = (f32x4)0.f, acc1 = (f32x4)0.f;
#pragma unroll
        for (int kb = 0; kb < 16; ++kb) {
            const int c = (kb * 4 + quad) ^ (l15 & 7);
            bf16x8 a = *(const bf16x8*)&As[((size_t)l15 * 64 + c) * 8];
            acc0 = __builtin_amdgcn_mfma_f32_16x16x32_bf16(a, B0[kb], acc0, 0, 0, 0);
            acc1 = __builtin_amdgcn_mfma_f32_16x16x32_bf16(a, B1[kb], acc1, 0, 0, 0);
        }

        __bf16* dst = pre + ((size_t)s_out * N_NODES + (size_t)tile * TILE_R + quad * 4) * D_OUT + cp0;
#pragma unroll
        for (int r = 0; r < 4; ++r) {
            dst[(size_t)r * D_OUT]      = (__bf16)acc0[r];
            dst[(size_t)r * D_OUT + 16] = (__bf16)acc1[r];
        }

        tile = next;
    }
}

// ---------------------------------------------------------------------------
// K3: coarse scatter — counting sort of one 3125-edge chunk into 64-row
// buckets (782/support). LDS sort + linear coalesced global write.
// Payload: (val_bits, r<<16 | col).
// ---------------------------------------------------------------------------
__global__ __launch_bounds__(512) void scatter_coarse(const float* __restrict__ adj_vals,
                                                      const int* __restrict__ adj_rows,
                                                      const int* __restrict__ adj_cols,
                                                      int* __restrict__ gcursor,
                                                      uint2* __restrict__ coarse) {
    __shared__ int hist[NB_S];
    __shared__ int excl[NB_S];
    __shared__ int lbase[NB_S];
    __shared__ int rankc[NB_S];
    __shared__ int sc[1024];
    __shared__ uint2 buf[CHUNK];                    // 25000 B

    const int bid = blockIdx.x;
    const int s   = bid >> 8;                       // support
    const int ch  = bid & 255;                      // chunk 0..255
    const int t   = threadIdx.x;

    for (int b = t; b < NB_S; b += 512) { hist[b] = 0; rankc[b] = 0; }
    __syncthreads();

    const int e0 = ch * CHUNK;
    int   rr[7]; int cc[7]; float vv[7];
#pragma unroll
    for (int i = 0; i < 7; ++i) {
        const int idx = i * 512 + t;
        if (idx < CHUNK) {
            const size_t src = (size_t)s * N_EDGES + e0 + idx;
            rr[i] = adj_rows[src];
            cc[i] = adj_cols[src];
            vv[i] = adj_vals[src];
            atomicAdd(&hist[rr[i] >> 6], 1);
        } else {
            rr[i] = -1; cc[i] = 0; vv[i] = 0.f;
        }
    }
    __syncthreads();

    // 1024-wide Hillis-Steele scan, 512 threads x 2 elements
    sc[t]       = (t       < NB_S) ? hist[t]       : 0;
    sc[t + 512] = (t + 512 < NB_S) ? hist[t + 512] : 0;
    __syncthreads();
    for (int off = 1; off < 1024; off <<= 1) {
        const int a0 = (t >= off) ? sc[t - off] : 0;
        const int a1 = sc[t + 512 - off];
        __syncthreads();
        sc[t]       += a0;
        sc[t + 512] += a1;
        __syncthreads();
    }
#pragma unroll
    for (int h = 0; h < 2; ++h) {
        const int b = t + h * 512;
        if (b < NB_S) {
            excl[b]  = sc[b] - hist[b];
            lbase[b] = hist[b] ? atomicAdd(&gcursor[s * NB_S + b], hist[b]) : 0;
        }
    }
    __syncthreads();

#pragma unroll
    for (int i = 0; i < 7; ++i) {
        if (rr[i] >= 0) {
            const int b   = rr[i] >> 6;
            const int pos = excl[b] + atomicAdd(&rankc[b], 1);
            buf[pos] = make_uint2(__float_as_uint(vv[i]),
                                  ((unsigned)rr[i] << 16) | (unsigned)cc[i]);
        }
    }
    __syncthreads();

    for (int i = t; i < CHUNK; i += 512) {
        const uint2 ed = buf[i];
        const int b   = (int)(ed.y >> 22);          // r>>6
        const int dst = lbase[b] + (i - excl[b]);
        if (dst < CAPF)                             // statistically impossible overflow guard
            coarse[(size_t)(s * NB_S + b) * CAPF + dst] = ed;
    }
}

// ---------------------------------------------------------------------------
// K4: fine sort + gather, merged. One block per 64-row bucket (782 blocks,
// 512 thr): sort BOTH supports' buckets by row into LDS (fine's proven
// algorithm), then gather from the LDS edge lists with gather_spmm's proven
// quarter-wave scheme, accumulate both supports in registers, bias+ReLU.
// Eliminates the `sorted` global round-trip + one dispatch.
// ---------------------------------------------------------------------------
__global__ __launch_bounds__(512) void fine_gather(const uint2* __restrict__ coarse,
                                                   const int* __restrict__ gcursor,
                                                   const uint4* __restrict__ pre_q,
                                                   const float* __restrict__ bias,
                                                   float* __restrict__ out) {
    __shared__ uint2 buf[2 * CAPF];                 // 20480 B (row-sorted, 2 supports)
    __shared__ int rex[2][64];
    __shared__ int rcnt[2][64];
    __shared__ int rh[64];
    __shared__ int rc[64];
    __shared__ int sd[64];

    const int bk = blockIdx.x;                      // 0..781
    const int t  = threadIdx.x;

    // ---- sort both supports' buckets by local row ----
#pragma unroll
    for (int s = 0; s < N_SUP; ++s) {
        if (t < 64) { rh[t] = 0; rc[t] = 0; }
        __syncthreads();

        const int bkt  = s * NB_S + bk;
        const size_t b0 = (size_t)bkt * CAPF;
        const int cnt  = min(gcursor[bkt], CAPF);

        uint2 ev0, ev1, ev2;                        // 3*512 = 1536 >= CAPF
        ev0 = make_uint2(0u, 0u); ev1 = ev0; ev2 = ev0;
        if (t < cnt)        { ev0 = coarse[b0 + t];        atomicAdd(&rh[(ev0.y >> 16) & 63], 1); }
        if (t + 512 < cnt)  { ev1 = coarse[b0 + t + 512];  atomicAdd(&rh[(ev1.y >> 16) & 63], 1); }
        if (t + 1024 < cnt) { ev2 = coarse[b0 + t + 1024]; atomicAdd(&rh[(ev2.y >> 16) & 63], 1); }
        __syncthreads();

        if (t < 64) sd[t] = rh[t];
        __syncthreads();
        for (int off = 1; off < 64; off <<= 1) {
            const int a = (t < 64 && t >= off) ? sd[t - off] : 0;
            __syncthreads();
            if (t < 64) sd[t] += a;
            __syncthreads();
        }
        if (t < 64) {
            rex[s][t]  = sd[t] - rh[t];
            rcnt[s][t] = rh[t];
        }
        __syncthreads();

        if (t < cnt) {
            const int rl = (ev0.y >> 16) & 63;
            buf[s * CAPF + rex[s][rl] + atomicAdd(&rc[rl], 1)] =
                make_uint2(ev0.x, ev0.y & 0xFFFFu);
        }
        if (t + 512 < cnt) {
            const int rl = (ev1.y >> 16) & 63;
            buf[s * CAPF + rex[s][rl] + atomicAdd(&rc[rl], 1)] =
                make_uint2(ev1.x, ev1.y & 0xFFFFu);
        }
        if (t + 1024 < cnt) {
            const int rl = (ev2.y >> 16) & 63;
            buf[s * CAPF + rex[s][rl] + atomicAdd(&rc[rl], 1)] =
                make_uint2(ev2.x, ev2.y & 0xFFFFu);
        }
        __syncthreads();
    }

    // ---- gather: 8 waves x 8 rows, both supports accumulated per row ----
    const int lane = t & 63;
    const int q    = lane >> 4;
    const int fl   = lane & 15;
    const int wv   = t >> 6;

    for (int ri = 0; ri < 8; ++ri) {
        const int rloc = wv * 8 + ri;
        const int row  = bk * 64 + rloc;

        float a[8];
#pragma unroll
        for (int k = 0; k < 8; ++k) a[k] = 0.f;

#pragma unroll
        for (int s = 0; s < N_SUP; ++s) {
            const int start = rex[s][rloc];
            const int cnt   = rcnt[s][rloc];
            const uint2* eb = buf + s * CAPF + start;
            const uint4* psup = pre_q + (size_t)s * N_NODES * 16 + fl;

            for (int e0 = 0; e0 < cnt; e0 += 64) {
                const int m = min(64, cnt - e0);
                int   c = 0;
                float v = 0.f;
                if (lane < m) {
                    const uint2 ed = eb[e0 + lane];
                    v = __uint_as_float(ed.x);
                    c = (int)ed.y;
                }
                const int steps = (m + 3) >> 2;

                auto step = [&](int jj) {
                    const int   idx = (jj < m) ? jj : 0;
                    float vj = __shfl(v, idx);
                    const int cj = __shfl(c, idx);
                    if (jj >= m) vj = 0.f;
                    const uint4 p = psup[(size_t)cj * 16];
                    a[0] += vj * __uint_as_float(p.x << 16);
                    a[1] += vj * __uint_as_float(p.x & 0xffff0000u);
                    a[2] += vj * __uint_as_float(p.y << 16);
                    a[3] += vj * __uint_as_float(p.y & 0xffff0000u);
                    a[4] += vj * __uint_as_float(p.z << 16);
                    a[5] += vj * __uint_as_float(p.z & 0xffff0000u);
                    a[6] += vj * __uint_as_float(p.w << 16);
                    a[7] += vj * __uint_as_float(p.w & 0xffff0000u);
                };
                int jj = 0;
                for (; jj + 1 < steps; jj += 2) {
                    step(jj * 4 + q);
                    step(jj * 4 + 4 + q);
                }
                if (jj < steps) step(jj * 4 + q);
            }
        }

#pragma unroll
        for (int k = 0; k < 8; ++k) {
            a[k] += __shfl_xor(a[k], 16);
            a[k] += __shfl_xor(a[k], 32);
        }

        if (lane < 16 && row < N_NODES) {
            const float4 b0 = *(const float4*)(bias + fl * 8);
            const float4 b1 = *(const float4*)(bias + fl * 8 + 4);
            float4 o0, o1;
            o0.x = fmaxf(a[0] + b0.x, 0.f);
            o0.y = fmaxf(a[1] + b0.y, 0.f);
            o0.z = fmaxf(a[2] + b0.z, 0.f);
            o0.w = fmaxf(a[3] + b0.w, 0.f);
            o1.x = fmaxf(a[4] + b1.x, 0.f);
            o1.y = fmaxf(a[5] + b1.y, 0.f);
            o1.z = fmaxf(a[6] + b1.z, 0.f);
            o1.w = fmaxf(a[7] + b1.w, 0.f);
            float* dst = out + (size_t)row * D_OUT + fl * 8;
            *(float4*)(dst)     = o0;
            *(float4*)(dst + 4) = o1;
        }
    }
}

extern "C" void kernel_launch(void* const* d_in, const int* in_sizes, int n_in,
                              void* d_out, int out_size, void* d_ws, size_t ws_size,
                              hipStream_t stream) {
    const float* x        = (const float*)d_in[0];
    const float* kernels  = (const float*)d_in[1];
    const float* bias     = (const float*)d_in[2];
    const float* adj_vals = (const float*)d_in[3];
    const int*   adj_rows = (const int*)d_in[4];
    const int*   adj_cols = (const int*)d_in[5];
    float* out = (float*)d_out;

    // ---- workspace layout ----
    char* ws = (char*)d_ws;
    size_t off = 0;
    auto alloc = [&](size_t bytes) {
        char* p = ws + off;
        off += (bytes + 255) & ~(size_t)255;
        return p;
    };
    __bf16* pre    = (__bf16*)alloc(sizeof(__bf16) * N_SUP * N_NODES * D_OUT); // 25.6 MB
    __bf16* wt2    = (__bf16*)alloc(sizeof(__bf16) * D_IN * N_COLS);           // 256 KB
    uint2*  coarse = (uint2*) alloc(sizeof(uint2)  * NB * CAPF);               // 16.0 MB
    int*    gcursor = (int*)alloc(sizeof(int) * NB);                           // 6.3 KB

    // K1: W convert + gcursor zero
    convert_w<<<(D_IN / 8) * N_COLS / 256, 256, 0, stream>>>(kernels, wt2, gcursor);

    // K2: GEMM (round-3 proven persistent kernel)
    gemm_bf16_v2<<<GGRID, 512, 0, stream>>>(x, wt2, pre);

    // K3: coarse scatter into 64-row buckets
    scatter_coarse<<<512, 512, 0, stream>>>(adj_vals, adj_rows, adj_cols,
                                            gcursor, coarse);

    // K4: fine sort + gather + bias + ReLU (merged)
    fine_gather<<<NB_S, 512, 0, stream>>>(coarse, gcursor, (const uint4*)pre,
                                          bias, out);
}